// Round 7
// baseline (191.378 us; speedup 1.0000x reference)
//
#include <hip/hip_runtime.h>

#define BATCH 8
#define CC 64
#define NN 4096
#define SCL 0.51006973f   // log2(e)/sqrt(8), folded into Q weights at prep time

typedef __attribute__((ext_vector_type(8))) short s16x8;
typedef __attribute__((ext_vector_type(4))) short s16x4;
typedef __attribute__((ext_vector_type(4))) float f32x4;
typedef __attribute__((ext_vector_type(2))) unsigned int uint2v;

__device__ __forceinline__ short f2bf(float f) {
  unsigned u = __builtin_bit_cast(unsigned, f);
  u += 0x7fffu + ((u >> 16) & 1u);
  return (short)(u >> 16);
}
__device__ __forceinline__ float bf2f(short h) {
  unsigned u = ((unsigned)(unsigned short)h) << 16;
  return __builtin_bit_cast(float, u);
}
__device__ __forceinline__ unsigned cvt_pk_bf16(float lo, float hi) {
  unsigned r;
  asm volatile("v_cvt_pk_bf16_f32 %0, %1, %2" : "=v"(r) : "v"(lo), "v"(hi));
  return r;
}

// key permutation within a 64-group (fragment storage order for attn A-operand)
__device__ __forceinline__ int kperm(int kk) {
  int hh = (kk >> 5) & 1, g = (kk >> 3) & 3, c = kk & 7;
  return hh * 32 + (c < 4 ? (g << 2) + c : 16 + ((g ^ 2) << 2) + (c - 4));
}

// ---------------- kernel 0: effective weights + concatenated proj weights ----------------
__global__ void prep_weights_kernel(const float* __restrict__ wz, const float* __restrict__ bz,
                                    const float* __restrict__ wo, const float* __restrict__ bo,
                                    const float* __restrict__ wg, const float* __restrict__ bg,
                                    const float* __restrict__ wi, const float* __restrict__ bi,
                                    const float* __restrict__ wq, const float* __restrict__ bq,
                                    const float* __restrict__ wkh, const float* __restrict__ bkh,
                                    const float* __restrict__ wvh, const float* __restrict__ bvh,
                                    const float* __restrict__ wkm, const float* __restrict__ bkm,
                                    const float* __restrict__ wvm, const float* __restrict__ bvm,
                                    short* __restrict__ Weff, float* __restrict__ beff,
                                    short* __restrict__ Wcat, float* __restrict__ bias) {
  int i = blockIdx.x * 256 + threadIdx.x;
  const float* wjs[3] = {wo, wg, wi};
  const float* bjs[3] = {bo, bg, bi};
  const float gsc[3] = {1.44269504f, 2.88539008f, 1.44269504f};
  if (i < 36864) {
    int j = i / 12288, rem = i % 12288, o = rem / 192, k = rem % 192;
    const float* wj = wjs[j];
    float v;
    if (k < 64) {
      v = wj[o * 128 + k];
    } else {
      v = 0.f;
      #pragma unroll 8
      for (int t = 0; t < 64; ++t) v += wj[o * 128 + 64 + t] * wz[t * 128 + (k - 64)];
    }
    Weff[i] = f2bf(v * gsc[j]);
  } else if (i < 37056) {
    int i2 = i - 36864;
    int j = i2 >> 6, o = i2 & 63;
    const float* wj = wjs[j];
    float v = bjs[j][o];
    #pragma unroll 8
    for (int t = 0; t < 64; ++t) v += wj[o * 128 + 64 + t] * bz[t];
    beff[i2] = v * gsc[j];
  } else if (i < 47296) {
    int i2 = i - 37056;
    int src = i2 / 5120, rem = i2 % 5120, row = rem >> 6, col = rem & 63;
    float v;
    if (src == 0) {
      if (row < 64) v = wvh[row * 64 + col];
      else if (row < 72) v = wq[(row - 64) * 64 + col] * SCL;
      else v = wkh[(row - 72) * 64 + col];
    } else {
      if (row < 64) v = wvm[row * 64 + col];
      else if (row < 72) v = wkm[(row - 64) * 64 + col];
      else v = 0.f;
    }
    Wcat[i2] = f2bf(v);
  } else if (i < 47456) {
    int i3 = i - 47296;
    int src = i3 / 80, row = i3 % 80;
    float v;
    if (src == 0) v = (row < 64) ? bvh[row] : (row < 72 ? bq[row - 64] * SCL : bkh[row - 72]);
    else          v = (row < 64) ? bvm[row] : (row < 72 ? bkm[row - 64] : 0.f);
    bias[i3] = v;
  }
}

// ---------------- kernel 1: MFMA projections v3 ----------------
// grid 1024 = b(8) x ntile(64) x src(2); 4 waves, 64 n per block.
// float4 input loads; V written through an LDS bounce for coalesced b128 stores.
__global__ __launch_bounds__(256) void proj_kernel(
    const float* __restrict__ H_in, const float* __restrict__ M_prev,
    const short* __restrict__ Wcat, const float* __restrict__ bias,
    short* __restrict__ Qt, short* __restrict__ Kht, short* __restrict__ Kmt,
    short* __restrict__ Vh, short* __restrict__ Vm) {
  int src = blockIdx.x & 1;
  int n0 = ((blockIdx.x >> 1) & 63) << 6;
  int b = blockIdx.x >> 7;
  int tid = threadIdx.x, w = tid >> 6, l = tid & 63, lg = l >> 4, ll = l & 15;

  const float* __restrict__ X = src ? M_prev : H_in;
  short* __restrict__ Vp = src ? Vm : Vh;

  __shared__ __align__(16) short Xt[64][68];  // [n][c], +4 pad
  __shared__ __align__(16) short Ot[64][76];  // [o][n], +12 pad (bank-spread)

  {
    int c = tid & 63, q = tid >> 6;
    const float* xs = X + ((size_t)((b << 6) + c)) * NN + n0 + q * 16;
    #pragma unroll
    for (int j = 0; j < 4; ++j) {
      float4 v = *(const float4*)(xs + j * 4);
      Xt[q * 16 + j * 4 + 0][c] = f2bf(v.x);
      Xt[q * 16 + j * 4 + 1][c] = f2bf(v.y);
      Xt[q * 16 + j * 4 + 2][c] = f2bf(v.z);
      Xt[q * 16 + j * 4 + 3][c] = f2bf(v.w);
    }
  }
  __syncthreads();

  f32x4 acc[5];
  #pragma unroll
  for (int ot = 0; ot < 5; ++ot)
    #pragma unroll
    for (int r = 0; r < 4; ++r) acc[ot][r] = bias[src * 80 + ot * 16 + lg * 4 + r];

  #pragma unroll
  for (int kk = 0; kk < 2; ++kk) {
    s16x8 bx = *(const s16x8*)&Xt[w * 16 + ll][kk * 32 + lg * 8];
    #pragma unroll
    for (int ot = 0; ot < 5; ++ot) {
      s16x8 aw = *(const s16x8*)(Wcat + ((size_t)(src * 80 + ot * 16 + ll)) * 64 + kk * 32 + lg * 8);
      acc[ot] = __builtin_amdgcn_mfma_f32_16x16x32_bf16(aw, bx, acc[ot], 0, 0, 0);
    }
  }

  // V rows (ot 0..3) -> LDS bounce
  #pragma unroll
  for (int ot = 0; ot < 4; ++ot)
    #pragma unroll
    for (int r = 0; r < 4; ++r)
      Ot[ot * 16 + lg * 4 + r][w * 16 + ll] = f2bf(acc[ot][r]);

  // Q/K (rows 64..79): scalar stores (small)
  {
    int n = n0 + w * 16 + ll;
    int pr = (n & ~63) + kperm(n & 63);
    #pragma unroll
    for (int r = 0; r < 4; ++r) {
      float v = acc[4][r];
      if (src == 0) {
        if (lg < 2) Qt[((size_t)(b * NN + n)) * 8 + (lg * 4 + r)] = f2bf(v);
        else        Kht[((size_t)(b * NN + pr)) * 8 + ((lg - 2) * 4 + r)] = f2bf(v);
      } else {
        if (lg < 2) Kmt[((size_t)(b * NN + pr)) * 8 + (lg * 4 + r)] = f2bf(v);
      }
    }
  }
  __syncthreads();

  // coalesced V stores: 512 chunks of 16B; thread t -> chunks t, t+256
  #pragma unroll
  for (int h = 0; h < 2; ++h) {
    int ci = tid + h * 256;
    int row = ci >> 3, seg = ci & 7;
    *(s16x8*)(Vp + ((size_t)((b << 6) + row)) * NN + n0 + seg * 8) =
        *(const s16x8*)&Ot[row][seg * 8];
  }
}

// ---------------- kernel 2: attention (key-split 2-way) ----------------
// grid 2048 = kh(2) x b(8) x s(2) x qt(64); BK=64, LDS 18KB.
// Unnormalized partial Z (bf16) + denominator (f32) out; combine in gates.
__global__ __launch_bounds__(256, 8) void attn_kernel(
    const short* __restrict__ Qt, const short* __restrict__ Kht, const short* __restrict__ Kmt,
    const short* __restrict__ Vh, const short* __restrict__ Vm,
    short* __restrict__ Zp, float* __restrict__ dnb) {
  unsigned vb = (blockIdx.x & 7) * 256 + (blockIdx.x >> 3);
  int kh = vb >> 10;
  int b  = (vb >> 7) & 7;
  int s  = (vb >> 6) & 1;
  int q0 = (vb & 63) << 6;
  int tid = threadIdx.x;
  int w = tid >> 6, l = tid & 63, lg = l >> 4, ll = l & 15;
  const bool lo32 = (l < 32);

  const short* __restrict__ Kp = s ? Kmt : Kht;
  const short* __restrict__ Vp = s ? Vm : Vh;

  __shared__ __align__(16) short Vt[2][64][64];   // 16KB, XOR-swizzled content
  __shared__ __align__(16) short Ktl[2][64][8];   // 2KB, fragment-ordered rows
  short* VtF = &Vt[0][0][0];
  short* KtF = &Ktl[0][0][0];

  s16x8 bq = {};
  if (lg == 0) bq = *(const s16x8*)(Qt + ((size_t)(b * NN + q0 + w * 16 + ll)) * 8);
  s16x8 ones;
  #pragma unroll
  for (int i = 0; i < 8; ++i) ones[i] = (short)0x3F80;

  f32x4 accZ[4];
  f32x4 accDn = {0.f, 0.f, 0.f, 0.f};
  #pragma unroll
  for (int cs = 0; cs < 4; ++cs) accZ[cs] = (f32x4){0.f, 0.f, 0.f, 0.f};

  const int vOff0 = ll * 64 + ((lg ^ (ll & 7)) << 3);
  const int vOff1 = ll * 64 + (((lg ^ 4) ^ (ll & 7)) << 3);
  const int kOff  = ll * 8;

  const int row0 = w * 8 + (l >> 3);
  const int swz  = ((l & 7) ^ (l >> 3)) << 3;
  const short* vsrc0 = Vp + ((size_t)((b << 6) + row0)) * NN + kh * 2048 + swz;
  const short* vsrc1 = Vp + ((size_t)((b << 6) + 32 + row0)) * NN + kh * 2048 + swz;
  const short* ksrc  = Kp + ((size_t)(b * NN) + kh * 2048 + l) * 8;

#define GLDS(src_, dst_) \
  __builtin_amdgcn_global_load_lds((const __attribute__((address_space(1))) void*)(src_), \
                                   (__attribute__((address_space(3))) void*)(dst_), 16, 0, 0)
#define STAGE(bufL, ktL) do { \
    GLDS(vsrc0 + (ktL) * 64, VtF + (bufL) * 4096 + w * 512); \
    GLDS(vsrc1 + (ktL) * 64, VtF + (bufL) * 4096 + 2048 + w * 512); \
    if (w == 0) GLDS(ksrc + (ktL) * 512, KtF + (bufL) * 512); \
  } while (0)

  auto compute = [&](int bufL) {
    float p[4][4];
    #pragma unroll
    for (int hh = 0; hh < 2; ++hh) {
      #pragma unroll
      for (int par = 0; par < 2; ++par) {
        s16x8 ak = *(const s16x8*)(KtF + bufL * 512 + (hh * 32 + par * 16) * 8 + kOff);
        f32x4 sc = __builtin_amdgcn_mfma_f32_16x16x32_bf16(ak, bq, (f32x4){0.f,0.f,0.f,0.f}, 0, 0, 0);
        #pragma unroll
        for (int r = 0; r < 4; ++r) p[hh * 2 + par][r] = __builtin_amdgcn_exp2f(sc[r]);
      }
    }
    unsigned wkv[4][2];
    #pragma unroll
    for (int ks = 0; ks < 4; ++ks) {
      wkv[ks][0] = cvt_pk_bf16(p[ks][0], p[ks][1]);
      wkv[ks][1] = cvt_pk_bf16(p[ks][2], p[ks][3]);
    }
    #pragma unroll
    for (int hh = 0; hh < 2; ++hh) {
      unsigned o0 = wkv[hh * 2 + 1][0], o1 = wkv[hh * 2 + 1][1];
      uint2v pr0 = __builtin_amdgcn_permlane32_swap(o0, o0, false, false);
      uint2v pr1 = __builtin_amdgcn_permlane32_swap(o1, o1, false, false);
      unsigned sw0 = lo32 ? pr0.y : pr0.x;
      unsigned sw1 = lo32 ? pr1.y : pr1.x;
      union { unsigned u[4]; s16x8 v; } bpu;
      bpu.u[0] = wkv[hh * 2][0];
      bpu.u[1] = wkv[hh * 2][1];
      bpu.u[2] = sw0;
      bpu.u[3] = sw1;
      s16x8 bp = bpu.v;
      accDn = __builtin_amdgcn_mfma_f32_16x16x32_bf16(ones, bp, accDn, 0, 0, 0);
      const int vo = hh ? vOff1 : vOff0;
      #pragma unroll
      for (int cs = 0; cs < 4; ++cs) {
        s16x8 av = *(const s16x8*)(VtF + bufL * 4096 + cs * 1024 + vo);
        accZ[cs] = __builtin_amdgcn_mfma_f32_16x16x32_bf16(av, bp, accZ[cs], 0, 0, 0);
      }
    }
  };

  STAGE(0, 0);
  #pragma unroll 1
  for (int kt2 = 0; kt2 < 16; ++kt2) {
    int kt = kt2 * 2;
    asm volatile("s_waitcnt vmcnt(0)" ::: "memory");
    __builtin_amdgcn_s_barrier();
    STAGE(1, kt + 1);
    compute(0);
    asm volatile("s_waitcnt vmcnt(0)" ::: "memory");
    __builtin_amdgcn_s_barrier();
    if (kt2 < 15) STAGE(0, kt + 2);
    compute(1);
  }

  #pragma unroll
  for (int cs = 0; cs < 4; ++cs) {
    s16x4 o4;
    #pragma unroll
    for (int r = 0; r < 4; ++r) o4[r] = f2bf(accZ[cs][r]);
    *(s16x4*)(Zp + ((size_t)((kh * 8 + b) * NN + q0 + w * 16 + ll)) * 128 + s * 64 + cs * 16 + lg * 4) = o4;
  }
  if (l < 16)
    dnb[((size_t)(kh * 16 + b * 2 + s)) * NN + q0 + w * 16 + l] = accDn[0];
#undef STAGE
#undef GLDS
}

// ---------------- kernel 3: fused gates + elementwise ----------------
// grid 1024 = b(8) x ntile(128); 32 n per block. Stages H (float4 from H_in) +
// combined Z into Xt, 36 MFMAs/wave, sigmoid/tanh epilogue + cell update.
__global__ __launch_bounds__(256) void gates_kernel(
    const float* __restrict__ H_in, const float* __restrict__ M_prev,
    const short* __restrict__ Zp, const float* __restrict__ dnb,
    const short* __restrict__ Weff, const float* __restrict__ beff,
    float* __restrict__ out) {
  int b = blockIdx.x >> 7;
  int n0 = (blockIdx.x & 127) << 5;
  int tid = threadIdx.x, w = tid >> 6, l = tid & 63, lg = l >> 4, ll = l & 15;
  __shared__ __align__(16) short Xt[32][200];  // [n][k], +8 pad

  {
    int c = tid & 63, q = tid >> 6;
    const float* xs = H_in + ((size_t)((b << 6) + c)) * NN + n0 + q * 8;
    #pragma unroll
    for (int j = 0; j < 2; ++j) {
      float4 v = *(const float4*)(xs + j * 4);
      Xt[q * 8 + j * 4 + 0][c] = f2bf(v.x);
      Xt[q * 8 + j * 4 + 1][c] = f2bf(v.y);
      Xt[q * 8 + j * 4 + 2][c] = f2bf(v.z);
      Xt[q * 8 + j * 4 + 3][c] = f2bf(v.w);
    }
  }
  {
    int n = tid >> 3, cq = tid & 7, sidx = cq >> 2;
    const short* z0 = Zp + ((size_t)(b * NN + n0 + n)) * 128 + cq * 16;
    const short* z1 = Zp + ((size_t)((8 + b) * NN + n0 + n)) * 128 + cq * 16;
    float d0 = dnb[((size_t)(b * 2 + sidx)) * NN + n0 + n];
    float d1 = dnb[((size_t)(16 + b * 2 + sidx)) * NN + n0 + n];
    float rd = __builtin_amdgcn_rcpf(d0 + d1);
    s16x8 a0 = *(const s16x8*)z0;
    s16x8 a1 = *(const s16x8*)z1;
    s16x8 b0 = *(const s16x8*)(z0 + 8);
    s16x8 b1 = *(const s16x8*)(z1 + 8);
    s16x8 o0, o1;
    #pragma unroll
    for (int j = 0; j < 8; ++j) {
      o0[j] = f2bf((bf2f(a0[j]) + bf2f(a1[j])) * rd);
      o1[j] = f2bf((bf2f(b0[j]) + bf2f(b1[j])) * rd);
    }
    *(s16x8*)&Xt[n][64 + cq * 16] = o0;
    *(s16x8*)&Xt[n][64 + cq * 16 + 8] = o1;
  }
  __syncthreads();

  f32x4 acc[3][2];
  #pragma unroll
  for (int j = 0; j < 3; ++j)
    #pragma unroll
    for (int ns = 0; ns < 2; ++ns)
      #pragma unroll
      for (int r = 0; r < 4; ++r) acc[j][ns][r] = beff[j * 64 + w * 16 + lg * 4 + r];

  #pragma unroll
  for (int kk = 0; kk < 6; ++kk) {
    s16x8 aw[3];
    #pragma unroll
    for (int j = 0; j < 3; ++j)
      aw[j] = *(const s16x8*)(Weff + ((size_t)(j * 64 + w * 16 + ll)) * 192 + kk * 32 + lg * 8);
    #pragma unroll
    for (int ns = 0; ns < 2; ++ns) {
      s16x8 bx = *(const s16x8*)&Xt[ns * 16 + ll][kk * 32 + lg * 8];
      #pragma unroll
      for (int j = 0; j < 3; ++j)
        acc[j][ns] = __builtin_amdgcn_mfma_f32_16x16x32_bf16(aw[j], bx, acc[j][ns], 0, 0, 0);
    }
  }

  float* Hout = out;
  float* Mout = out + (size_t)BATCH * CC * NN;
  #pragma unroll
  for (int ns = 0; ns < 2; ++ns) {
    #pragma unroll
    for (int r = 0; r < 4; ++r) {
      int c = w * 16 + lg * 4 + r;
      int n = n0 + ns * 16 + ll;
      size_t idx = ((size_t)((b << 6) + c)) * NN + n;
      float xo = acc[0][ns][r], xg = acc[1][ns][r], xi = acc[2][ns][r];
      float o  = __builtin_amdgcn_rcpf(1.f + __builtin_amdgcn_exp2f(-xo));
      float g  = 2.f * __builtin_amdgcn_rcpf(1.f + __builtin_amdgcn_exp2f(-xg)) - 1.f;
      float ii = __builtin_amdgcn_rcpf(1.f + __builtin_amdgcn_exp2f(-xi));
      float m  = M_prev[idx];
      float mt = (1.f - ii) * m + ii * g;
      Mout[idx] = mt;
      Hout[idx] = o * mt;
    }
  }
}

extern "C" void kernel_launch(void* const* d_in, const int* in_sizes, int n_in,
                              void* d_out, int out_size, void* d_ws, size_t ws_size,
                              hipStream_t stream) {
  (void)in_sizes; (void)n_in; (void)out_size; (void)ws_size;
  const float* H_in  = (const float*)d_in[0];
  const float* M_prev= (const float*)d_in[1];
  const float* wq  = (const float*)d_in[2];
  const float* bq  = (const float*)d_in[3];
  const float* wkh = (const float*)d_in[4];
  const float* bkh = (const float*)d_in[5];
  const float* wvh = (const float*)d_in[6];
  const float* bvh = (const float*)d_in[7];
  const float* wkm = (const float*)d_in[8];
  const float* bkm = (const float*)d_in[9];
  const float* wvm = (const float*)d_in[10];
  const float* bvm = (const float*)d_in[11];
  const float* wz  = (const float*)d_in[12];
  const float* bz  = (const float*)d_in[13];
  const float* wo  = (const float*)d_in[14];
  const float* bo  = (const float*)d_in[15];
  const float* wg  = (const float*)d_in[16];
  const float* bg  = (const float*)d_in[17];
  const float* wi  = (const float*)d_in[18];
  const float* bi  = (const float*)d_in[19];

  char* ws = (char*)d_ws;
  size_t off = 0;
  auto alloc = [&](size_t bytes) -> void* {
    void* p = ws + off;
    off += (bytes + 255) & ~(size_t)255;
    return p;
  };
  short* Weff = (short*)alloc(3 * 64 * 192 * 2);
  float* beff = (float*)alloc(192 * 4);
  short* Wcat = (short*)alloc(2 * 80 * 64 * 2);
  float* bias = (float*)alloc(160 * 4);
  short* Qt   = (short*)alloc((size_t)BATCH * NN * 8 * 2);
  short* Kht  = (short*)alloc((size_t)BATCH * NN * 8 * 2);
  short* Kmt  = (short*)alloc((size_t)BATCH * NN * 8 * 2);
  short* Vh   = (short*)alloc((size_t)BATCH * CC * NN * 2);
  short* Vm   = (short*)alloc((size_t)BATCH * CC * NN * 2);
  short* Zp   = (short*)alloc((size_t)2 * BATCH * NN * 128 * 2);  // 16MB (2 key-halves)
  float* dnb  = (float*)alloc((size_t)2 * BATCH * 2 * NN * 4);    // 512KB

  prep_weights_kernel<<<186, 256, 0, stream>>>(wz, bz, wo, bo, wg, bg, wi, bi,
                                               wq, bq, wkh, bkh, wvh, bvh, wkm, bkm, wvm, bvm,
                                               Weff, beff, Wcat, bias);
  proj_kernel<<<1024, 256, 0, stream>>>(H_in, M_prev, Wcat, bias, Qt, Kht, Kmt, Vh, Vm);
  attn_kernel<<<2048, 256, 0, stream>>>(Qt, Kht, Kmt, Vh, Vm, Zp, dnb);
  gates_kernel<<<1024, 256, 0, stream>>>(H_in, M_prev, Zp, dnb, Weff, beff, (float*)d_out);
}

// Round 8
// 183.757 us; speedup vs baseline: 1.0415x; 1.0415x over previous
//
#include <hip/hip_runtime.h>

#define BATCH 8
#define CC 64
#define NN 4096
#define SCL 0.51006973f   // log2(e)/sqrt(8), folded into Q weights at prep time

typedef __attribute__((ext_vector_type(8))) short s16x8;
typedef __attribute__((ext_vector_type(4))) short s16x4;
typedef __attribute__((ext_vector_type(4))) float f32x4;
typedef __attribute__((ext_vector_type(2))) unsigned int uint2v;

__device__ __forceinline__ short f2bf(float f) {
  unsigned u = __builtin_bit_cast(unsigned, f);
  u += 0x7fffu + ((u >> 16) & 1u);
  return (short)(u >> 16);
}
__device__ __forceinline__ float bf2f(short h) {
  unsigned u = ((unsigned)(unsigned short)h) << 16;
  return __builtin_bit_cast(float, u);
}
__device__ __forceinline__ unsigned cvt_pk_bf16(float lo, float hi) {
  unsigned r;
  asm volatile("v_cvt_pk_bf16_f32 %0, %1, %2" : "=v"(r) : "v"(lo), "v"(hi));
  return r;
}

// key permutation within a 64-group (fragment storage order for attn A-operand)
__device__ __forceinline__ int kperm(int kk) {
  int hh = (kk >> 5) & 1, g = (kk >> 3) & 3, c = kk & 7;
  return hh * 32 + (c < 4 ? (g << 2) + c : 16 + ((g ^ 2) << 2) + (c - 4));
}

// ---------------- kernel 0: effective weights + concatenated proj weights ----------------
__global__ void prep_weights_kernel(const float* __restrict__ wz, const float* __restrict__ bz,
                                    const float* __restrict__ wo, const float* __restrict__ bo,
                                    const float* __restrict__ wg, const float* __restrict__ bg,
                                    const float* __restrict__ wi, const float* __restrict__ bi,
                                    const float* __restrict__ wq, const float* __restrict__ bq,
                                    const float* __restrict__ wkh, const float* __restrict__ bkh,
                                    const float* __restrict__ wvh, const float* __restrict__ bvh,
                                    const float* __restrict__ wkm, const float* __restrict__ bkm,
                                    const float* __restrict__ wvm, const float* __restrict__ bvm,
                                    short* __restrict__ Weff, float* __restrict__ beff,
                                    short* __restrict__ Wcat, float* __restrict__ bias) {
  int i = blockIdx.x * 256 + threadIdx.x;
  const float* wjs[3] = {wo, wg, wi};
  const float* bjs[3] = {bo, bg, bi};
  const float gsc[3] = {1.44269504f, 2.88539008f, 1.44269504f};
  if (i < 36864) {
    int j = i / 12288, rem = i % 12288, o = rem / 192, k = rem % 192;
    const float* wj = wjs[j];
    float v;
    if (k < 64) {
      v = wj[o * 128 + k];
    } else {
      v = 0.f;
      #pragma unroll 8
      for (int t = 0; t < 64; ++t) v += wj[o * 128 + 64 + t] * wz[t * 128 + (k - 64)];
    }
    Weff[i] = f2bf(v * gsc[j]);
  } else if (i < 37056) {
    int i2 = i - 36864;
    int j = i2 >> 6, o = i2 & 63;
    const float* wj = wjs[j];
    float v = bjs[j][o];
    #pragma unroll 8
    for (int t = 0; t < 64; ++t) v += wj[o * 128 + 64 + t] * bz[t];
    beff[i2] = v * gsc[j];
  } else if (i < 47296) {
    int i2 = i - 37056;
    int src = i2 / 5120, rem = i2 % 5120, row = rem >> 6, col = rem & 63;
    float v;
    if (src == 0) {
      if (row < 64) v = wvh[row * 64 + col];
      else if (row < 72) v = wq[(row - 64) * 64 + col] * SCL;
      else v = wkh[(row - 72) * 64 + col];
    } else {
      if (row < 64) v = wvm[row * 64 + col];
      else if (row < 72) v = wkm[(row - 64) * 64 + col];
      else v = 0.f;
    }
    Wcat[i2] = f2bf(v);
  } else if (i < 47456) {
    int i3 = i - 47296;
    int src = i3 / 80, row = i3 % 80;
    float v;
    if (src == 0) v = (row < 64) ? bvh[row] : (row < 72 ? bq[row - 64] * SCL : bkh[row - 72]);
    else          v = (row < 64) ? bvm[row] : (row < 72 ? bkm[row - 64] : 0.f);
    bias[i3] = v;
  }
}

// ---------------- kernel 1: MFMA projections v3 ----------------
__global__ __launch_bounds__(256) void proj_kernel(
    const float* __restrict__ H_in, const float* __restrict__ M_prev,
    const short* __restrict__ Wcat, const float* __restrict__ bias,
    short* __restrict__ Qt, short* __restrict__ Kht, short* __restrict__ Kmt,
    short* __restrict__ Vh, short* __restrict__ Vm) {
  int src = blockIdx.x & 1;
  int n0 = ((blockIdx.x >> 1) & 63) << 6;
  int b = blockIdx.x >> 7;
  int tid = threadIdx.x, w = tid >> 6, l = tid & 63, lg = l >> 4, ll = l & 15;

  const float* __restrict__ X = src ? M_prev : H_in;
  short* __restrict__ Vp = src ? Vm : Vh;

  __shared__ __align__(16) short Xt[64][68];  // [n][c], +4 pad
  __shared__ __align__(16) short Ot[64][76];  // [o][n], +12 pad (bank-spread)

  {
    int c = tid & 63, q = tid >> 6;
    const float* xs = X + ((size_t)((b << 6) + c)) * NN + n0 + q * 16;
    #pragma unroll
    for (int j = 0; j < 4; ++j) {
      float4 v = *(const float4*)(xs + j * 4);
      Xt[q * 16 + j * 4 + 0][c] = f2bf(v.x);
      Xt[q * 16 + j * 4 + 1][c] = f2bf(v.y);
      Xt[q * 16 + j * 4 + 2][c] = f2bf(v.z);
      Xt[q * 16 + j * 4 + 3][c] = f2bf(v.w);
    }
  }
  __syncthreads();

  f32x4 acc[5];
  #pragma unroll
  for (int ot = 0; ot < 5; ++ot)
    #pragma unroll
    for (int r = 0; r < 4; ++r) acc[ot][r] = bias[src * 80 + ot * 16 + lg * 4 + r];

  #pragma unroll
  for (int kk = 0; kk < 2; ++kk) {
    s16x8 bx = *(const s16x8*)&Xt[w * 16 + ll][kk * 32 + lg * 8];
    #pragma unroll
    for (int ot = 0; ot < 5; ++ot) {
      s16x8 aw = *(const s16x8*)(Wcat + ((size_t)(src * 80 + ot * 16 + ll)) * 64 + kk * 32 + lg * 8);
      acc[ot] = __builtin_amdgcn_mfma_f32_16x16x32_bf16(aw, bx, acc[ot], 0, 0, 0);
    }
  }

  #pragma unroll
  for (int ot = 0; ot < 4; ++ot)
    #pragma unroll
    for (int r = 0; r < 4; ++r)
      Ot[ot * 16 + lg * 4 + r][w * 16 + ll] = f2bf(acc[ot][r]);

  {
    int n = n0 + w * 16 + ll;
    int pr = (n & ~63) + kperm(n & 63);
    #pragma unroll
    for (int r = 0; r < 4; ++r) {
      float v = acc[4][r];
      if (src == 0) {
        if (lg < 2) Qt[((size_t)(b * NN + n)) * 8 + (lg * 4 + r)] = f2bf(v);
        else        Kht[((size_t)(b * NN + pr)) * 8 + ((lg - 2) * 4 + r)] = f2bf(v);
      } else {
        if (lg < 2) Kmt[((size_t)(b * NN + pr)) * 8 + (lg * 4 + r)] = f2bf(v);
      }
    }
  }
  __syncthreads();

  #pragma unroll
  for (int h = 0; h < 2; ++h) {
    int ci = tid + h * 256;
    int row = ci >> 3, seg = ci & 7;
    *(s16x8*)(Vp + ((size_t)((b << 6) + row)) * NN + n0 + seg * 8) =
        *(const s16x8*)&Ot[row][seg * 8];
  }
}

// ---------------- kernel 2: attention v4 (2 q-tiles per wave) ----------------
// grid 1024 = kh(2) x b(8) x s(2) x qt(32); block covers 128 q; wave w owns
// q rows q0+w*32 .. +31 (two 16-q MFMA column tiles A/B sharing all K/V LDS reads).
__global__ __launch_bounds__(256, 4) void attn_kernel(
    const short* __restrict__ Qt, const short* __restrict__ Kht, const short* __restrict__ Kmt,
    const short* __restrict__ Vh, const short* __restrict__ Vm,
    short* __restrict__ Zp, float* __restrict__ dnb) {
  unsigned vb = (blockIdx.x & 7) * 128 + (blockIdx.x >> 3);
  int qt = vb & 31;
  int s  = (vb >> 5) & 1;
  int b  = (vb >> 6) & 7;
  int kh = (vb >> 9) & 1;
  int q0 = qt << 7;
  int tid = threadIdx.x;
  int w = tid >> 6, l = tid & 63, lg = l >> 4, ll = l & 15;
  const bool lo32 = (l < 32);

  const short* __restrict__ Kp = s ? Kmt : Kht;
  const short* __restrict__ Vp = s ? Vm : Vh;

  __shared__ __align__(16) short Vt[2][64][64];   // 16KB, XOR-swizzled content
  __shared__ __align__(16) short Ktl[2][64][8];   // 2KB, fragment-ordered rows
  short* VtF = &Vt[0][0][0];
  short* KtF = &Ktl[0][0][0];

  s16x8 bqA = {}, bqB = {};
  if (lg == 0) {
    bqA = *(const s16x8*)(Qt + ((size_t)(b * NN + q0 + w * 32 + ll)) * 8);
    bqB = *(const s16x8*)(Qt + ((size_t)(b * NN + q0 + w * 32 + 16 + ll)) * 8);
  }
  s16x8 ones;
  #pragma unroll
  for (int i = 0; i < 8; ++i) ones[i] = (short)0x3F80;
  const f32x4 fz = {0.f, 0.f, 0.f, 0.f};

  f32x4 accZA[4], accZB[4];
  f32x4 accDnA = fz, accDnB = fz;
  #pragma unroll
  for (int cs = 0; cs < 4; ++cs) { accZA[cs] = fz; accZB[cs] = fz; }

  const int vOff0 = ll * 64 + ((lg ^ (ll & 7)) << 3);
  const int vOff1 = ll * 64 + (((lg ^ 4) ^ (ll & 7)) << 3);
  const int kOff  = ll * 8;

  const int row0 = w * 8 + (l >> 3);
  const int swz  = ((l & 7) ^ (l >> 3)) << 3;
  const short* vsrc0 = Vp + ((size_t)((b << 6) + row0)) * NN + kh * 2048 + swz;
  const short* vsrc1 = Vp + ((size_t)((b << 6) + 32 + row0)) * NN + kh * 2048 + swz;
  const short* ksrc  = Kp + ((size_t)(b * NN) + kh * 2048 + l) * 8;

#define GLDS(src_, dst_) \
  __builtin_amdgcn_global_load_lds((const __attribute__((address_space(1))) void*)(src_), \
                                   (__attribute__((address_space(3))) void*)(dst_), 16, 0, 0)
#define STAGE(bufL, ktL) do { \
    GLDS(vsrc0 + (ktL) * 64, VtF + (bufL) * 4096 + w * 512); \
    GLDS(vsrc1 + (ktL) * 64, VtF + (bufL) * 4096 + 2048 + w * 512); \
    if (w == 0) GLDS(ksrc + (ktL) * 512, KtF + (bufL) * 512); \
  } while (0)

  auto compute = [&](int bufL) {
    #pragma unroll
    for (int hh = 0; hh < 2; ++hh) {
      float pA[2][4], pB[2][4];
      #pragma unroll
      for (int par = 0; par < 2; ++par) {
        s16x8 ak = *(const s16x8*)(KtF + bufL * 512 + (hh * 32 + par * 16) * 8 + kOff);
        f32x4 scA = __builtin_amdgcn_mfma_f32_16x16x32_bf16(ak, bqA, fz, 0, 0, 0);
        f32x4 scB = __builtin_amdgcn_mfma_f32_16x16x32_bf16(ak, bqB, fz, 0, 0, 0);
        #pragma unroll
        for (int r = 0; r < 4; ++r) {
          pA[par][r] = __builtin_amdgcn_exp2f(scA[r]);
          pB[par][r] = __builtin_amdgcn_exp2f(scB[r]);
        }
      }
      // pack (par0 words in-lane; par1 words via self-swap + select)
      unsigned a0 = cvt_pk_bf16(pA[0][0], pA[0][1]);
      unsigned a1 = cvt_pk_bf16(pA[0][2], pA[0][3]);
      unsigned a2 = cvt_pk_bf16(pA[1][0], pA[1][1]);
      unsigned a3 = cvt_pk_bf16(pA[1][2], pA[1][3]);
      unsigned b0 = cvt_pk_bf16(pB[0][0], pB[0][1]);
      unsigned b1 = cvt_pk_bf16(pB[0][2], pB[0][3]);
      unsigned b2 = cvt_pk_bf16(pB[1][0], pB[1][1]);
      unsigned b3 = cvt_pk_bf16(pB[1][2], pB[1][3]);
      uint2v prA0 = __builtin_amdgcn_permlane32_swap(a2, a2, false, false);
      uint2v prA1 = __builtin_amdgcn_permlane32_swap(a3, a3, false, false);
      uint2v prB0 = __builtin_amdgcn_permlane32_swap(b2, b2, false, false);
      uint2v prB1 = __builtin_amdgcn_permlane32_swap(b3, b3, false, false);
      union { unsigned u[4]; s16x8 v; } bpA, bpB;
      bpA.u[0] = a0; bpA.u[1] = a1;
      bpA.u[2] = lo32 ? prA0.y : prA0.x;
      bpA.u[3] = lo32 ? prA1.y : prA1.x;
      bpB.u[0] = b0; bpB.u[1] = b1;
      bpB.u[2] = lo32 ? prB0.y : prB0.x;
      bpB.u[3] = lo32 ? prB1.y : prB1.x;

      const int vo = hh ? vOff1 : vOff0;
      __builtin_amdgcn_s_setprio(1);
      accDnA = __builtin_amdgcn_mfma_f32_16x16x32_bf16(ones, bpA.v, accDnA, 0, 0, 0);
      accDnB = __builtin_amdgcn_mfma_f32_16x16x32_bf16(ones, bpB.v, accDnB, 0, 0, 0);
      #pragma unroll
      for (int cs = 0; cs < 4; ++cs) {
        s16x8 av = *(const s16x8*)(VtF + bufL * 4096 + cs * 1024 + vo);
        accZA[cs] = __builtin_amdgcn_mfma_f32_16x16x32_bf16(av, bpA.v, accZA[cs], 0, 0, 0);
        accZB[cs] = __builtin_amdgcn_mfma_f32_16x16x32_bf16(av, bpB.v, accZB[cs], 0, 0, 0);
      }
      __builtin_amdgcn_s_setprio(0);
    }
  };

  STAGE(0, 0);
  #pragma unroll 1
  for (int kt2 = 0; kt2 < 16; ++kt2) {
    int kt = kt2 * 2;
    asm volatile("s_waitcnt vmcnt(0)" ::: "memory");
    __builtin_amdgcn_s_barrier();
    STAGE(1, kt + 1);
    compute(0);
    asm volatile("s_waitcnt vmcnt(0)" ::: "memory");
    __builtin_amdgcn_s_barrier();
    if (kt2 < 15) STAGE(0, kt + 2);
    compute(1);
  }

  // unnormalized partial out + denominators
  int qA = q0 + w * 32 + ll;
  #pragma unroll
  for (int cs = 0; cs < 4; ++cs) {
    s16x4 oA, oB;
    #pragma unroll
    for (int r = 0; r < 4; ++r) { oA[r] = f2bf(accZA[cs][r]); oB[r] = f2bf(accZB[cs][r]); }
    *(s16x4*)(Zp + ((size_t)((kh * 8 + b) * NN + qA)) * 128 + s * 64 + cs * 16 + lg * 4) = oA;
    *(s16x4*)(Zp + ((size_t)((kh * 8 + b) * NN + qA + 16)) * 128 + s * 64 + cs * 16 + lg * 4) = oB;
  }
  if (l < 16) {
    dnb[((size_t)(kh * 16 + b * 2 + s)) * NN + q0 + w * 32 + l] = accDnA[0];
    dnb[((size_t)(kh * 16 + b * 2 + s)) * NN + q0 + w * 32 + 16 + l] = accDnB[0];
  }
#undef STAGE
#undef GLDS
}

// ---------------- kernel 3: fused gates + elementwise ----------------
__global__ __launch_bounds__(256) void gates_kernel(
    const float* __restrict__ H_in, const float* __restrict__ M_prev,
    const short* __restrict__ Zp, const float* __restrict__ dnb,
    const short* __restrict__ Weff, const float* __restrict__ beff,
    float* __restrict__ out) {
  int b = blockIdx.x >> 7;
  int n0 = (blockIdx.x & 127) << 5;
  int tid = threadIdx.x, w = tid >> 6, l = tid & 63, lg = l >> 4, ll = l & 15;
  __shared__ __align__(16) short Xt[32][200];  // [n][k], +8 pad

  {
    int c = tid & 63, q = tid >> 6;
    const float* xs = H_in + ((size_t)((b << 6) + c)) * NN + n0 + q * 8;
    #pragma unroll
    for (int j = 0; j < 2; ++j) {
      float4 v = *(const float4*)(xs + j * 4);
      Xt[q * 8 + j * 4 + 0][c] = f2bf(v.x);
      Xt[q * 8 + j * 4 + 1][c] = f2bf(v.y);
      Xt[q * 8 + j * 4 + 2][c] = f2bf(v.z);
      Xt[q * 8 + j * 4 + 3][c] = f2bf(v.w);
    }
  }
  {
    int n = tid >> 3, cq = tid & 7, sidx = cq >> 2;
    const short* z0 = Zp + ((size_t)(b * NN + n0 + n)) * 128 + cq * 16;
    const short* z1 = Zp + ((size_t)((8 + b) * NN + n0 + n)) * 128 + cq * 16;
    float d0 = dnb[((size_t)(b * 2 + sidx)) * NN + n0 + n];
    float d1 = dnb[((size_t)(16 + b * 2 + sidx)) * NN + n0 + n];
    float rd = __builtin_amdgcn_rcpf(d0 + d1);
    s16x8 a0 = *(const s16x8*)z0;
    s16x8 a1 = *(const s16x8*)z1;
    s16x8 b0 = *(const s16x8*)(z0 + 8);
    s16x8 b1 = *(const s16x8*)(z1 + 8);
    s16x8 o0, o1;
    #pragma unroll
    for (int j = 0; j < 8; ++j) {
      o0[j] = f2bf((bf2f(a0[j]) + bf2f(a1[j])) * rd);
      o1[j] = f2bf((bf2f(b0[j]) + bf2f(b1[j])) * rd);
    }
    *(s16x8*)&Xt[n][64 + cq * 16] = o0;
    *(s16x8*)&Xt[n][64 + cq * 16 + 8] = o1;
  }
  __syncthreads();

  f32x4 acc[3][2];
  #pragma unroll
  for (int j = 0; j < 3; ++j)
    #pragma unroll
    for (int ns = 0; ns < 2; ++ns)
      #pragma unroll
      for (int r = 0; r < 4; ++r) acc[j][ns][r] = beff[j * 64 + w * 16 + lg * 4 + r];

  #pragma unroll
  for (int kk = 0; kk < 6; ++kk) {
    s16x8 aw[3];
    #pragma unroll
    for (int j = 0; j < 3; ++j)
      aw[j] = *(const s16x8*)(Weff + ((size_t)(j * 64 + w * 16 + ll)) * 192 + kk * 32 + lg * 8);
    #pragma unroll
    for (int ns = 0; ns < 2; ++ns) {
      s16x8 bx = *(const s16x8*)&Xt[ns * 16 + ll][kk * 32 + lg * 8];
      #pragma unroll
      for (int j = 0; j < 3; ++j)
        acc[j][ns] = __builtin_amdgcn_mfma_f32_16x16x32_bf16(aw[j], bx, acc[j][ns], 0, 0, 0);
    }
  }

  float* Hout = out;
  float* Mout = out + (size_t)BATCH * CC * NN;
  #pragma unroll
  for (int ns = 0; ns < 2; ++ns) {
    #pragma unroll
    for (int r = 0; r < 4; ++r) {
      int c = w * 16 + lg * 4 + r;
      int n = n0 + ns * 16 + ll;
      size_t idx = ((size_t)((b << 6) + c)) * NN + n;
      float xo = acc[0][ns][r], xg = acc[1][ns][r], xi = acc[2][ns][r];
      float o  = __builtin_amdgcn_rcpf(1.f + __builtin_amdgcn_exp2f(-xo));
      float g  = 2.f * __builtin_amdgcn_rcpf(1.f + __builtin_amdgcn_exp2f(-xg)) - 1.f;
      float ii = __builtin_amdgcn_rcpf(1.f + __builtin_amdgcn_exp2f(-xi));
      float m  = M_prev[idx];
      float mt = (1.f - ii) * m + ii * g;
      Mout[idx] = mt;
      Hout[idx] = o * mt;
    }
  }
}

extern "C" void kernel_launch(void* const* d_in, const int* in_sizes, int n_in,
                              void* d_out, int out_size, void* d_ws, size_t ws_size,
                              hipStream_t stream) {
  (void)in_sizes; (void)n_in; (void)out_size; (void)ws_size;
  const float* H_in  = (const float*)d_in[0];
  const float* M_prev= (const float*)d_in[1];
  const float* wq  = (const float*)d_in[2];
  const float* bq  = (const float*)d_in[3];
  const float* wkh = (const float*)d_in[4];
  const float* bkh = (const float*)d_in[5];
  const float* wvh = (const float*)d_in[6];
  const float* bvh = (const float*)d_in[7];
  const float* wkm = (const float*)d_in[8];
  const float* bkm = (const float*)d_in[9];
  const float* wvm = (const float*)d_in[10];
  const float* bvm = (const float*)d_in[11];
  const float* wz  = (const float*)d_in[12];
  const float* bz  = (const float*)d_in[13];
  const float* wo  = (const float*)d_in[14];
  const float* bo  = (const float*)d_in[15];
  const float* wg  = (const float*)d_in[16];
  const float* bg  = (const float*)d_in[17];
  const float* wi  = (const float*)d_in[18];
  const float* bi  = (const float*)d_in[19];

  char* ws = (char*)d_ws;
  size_t off = 0;
  auto alloc = [&](size_t bytes) -> void* {
    void* p = ws + off;
    off += (bytes + 255) & ~(size_t)255;
    return p;
  };
  short* Weff = (short*)alloc(3 * 64 * 192 * 2);
  float* beff = (float*)alloc(192 * 4);
  short* Wcat = (short*)alloc(2 * 80 * 64 * 2);
  float* bias = (float*)alloc(160 * 4);
  short* Qt   = (short*)alloc((size_t)BATCH * NN * 8 * 2);
  short* Kht  = (short*)alloc((size_t)BATCH * NN * 8 * 2);
  short* Kmt  = (short*)alloc((size_t)BATCH * NN * 8 * 2);
  short* Vh   = (short*)alloc((size_t)BATCH * CC * NN * 2);
  short* Vm   = (short*)alloc((size_t)BATCH * CC * NN * 2);
  short* Zp   = (short*)alloc((size_t)2 * BATCH * NN * 128 * 2);  // 16MB (2 key-halves)
  float* dnb  = (float*)alloc((size_t)2 * BATCH * 2 * NN * 4);    // 512KB

  prep_weights_kernel<<<186, 256, 0, stream>>>(wz, bz, wo, bo, wg, bg, wi, bi,
                                               wq, bq, wkh, bkh, wvh, bvh, wkm, bkm, wvm, bvm,
                                               Weff, beff, Wcat, bias);
  proj_kernel<<<1024, 256, 0, stream>>>(H_in, M_prev, Wcat, bias, Qt, Kht, Kmt, Vh, Vm);
  attn_kernel<<<1024, 256, 0, stream>>>(Qt, Kht, Kmt, Vh, Vm, Zp, dnb);
  gates_kernel<<<1024, 256, 0, stream>>>(H_in, M_prev, Zp, dnb, Weff, beff, (float*)d_out);
}